// Round 2
// baseline (362.173 us; speedup 1.0000x reference)
//
#include <hip/hip_runtime.h>

// Problem constants (B,D,H,O) = (16,128,2048,4), W = O*H+O = 8196
#define BB 16
#define DD 128
#define HH 2048
#define OO 4
#define WTOT 8196
#define OHH 8192   // O*H
#define KC 32      // k-rows per quad block
#define NQUAD 512  // 4 o * 2 col-tiles * 64 k-chunks
#define NCROSS 32  // 4 o * 8 k-blocks

// ws layout (floats):
//   hT     [0, 32768)          h transposed: hT[j*16+b]
//   qpart  [32768, 40960)      per-quad-block partials [block][b]
//   xu     [40960, 41472)      cross-term u partials   [block][b]
//   xp     [41472, 41984)      prediction partials     [block][b]

// h = relu(x @ W1^T + b1), stored transposed: hT[j*16+b]
__global__ __launch_bounds__(256) void k_prep(const float* __restrict__ x,
                                              const float* __restrict__ W1,
                                              const float* __restrict__ b1,
                                              float* __restrict__ hT) {
    __shared__ float xs[DD * BB];   // xs[d*16+b]
    int tid = threadIdx.x;
    for (int i = tid; i < DD * BB; i += 256) {
        int b = i & 15, d = i >> 4;
        xs[i] = x[b * DD + d];
    }
    __syncthreads();
    int b = tid & 15;
    int j = blockIdx.x * 16 + (tid >> 4);
    const float4* W1v = (const float4*)(W1 + (size_t)j * DD);
    float acc = 0.0f;
#pragma unroll
    for (int dd = 0; dd < DD / 4; ++dd) {
        float4 w = W1v[dd];
        acc = fmaf(xs[(dd * 4 + 0) * 16 + b], w.x, acc);
        acc = fmaf(xs[(dd * 4 + 1) * 16 + b], w.y, acc);
        acc = fmaf(xs[(dd * 4 + 2) * 16 + b], w.z, acc);
        acc = fmaf(xs[(dd * 4 + 3) * 16 + b], w.w, acc);
    }
    acc += b1[j];
    hT[j * 16 + b] = acc > 0.0f ? acc : 0.0f;
}

// Blocks [0,512): quadratic form partials over the 4 diagonal HxH blocks of C.
//   block (o, ct, kc): rows kc*32..+31, cols ct*1024..+1023 of C_o.
//   Thread owns 4 consecutive cols (float4 C loads). h rows staged in LDS.
// Blocks [512,544): bias row/col cross terms + prediction partials.
__global__ __launch_bounds__(256) void k_main(const float* __restrict__ C,
                                              const float* __restrict__ hT,
                                              const float* __restrict__ W2,
                                              float* __restrict__ qpart,
                                              float* __restrict__ xu,
                                              float* __restrict__ xp) {
    int bid = blockIdx.x;
    int tid = threadIdx.x;
    __shared__ float sh[KC * 16];   // 2 KB staged h rows
    __shared__ float red[4 * 16];

    if (bid < NQUAD) {
        int o  = bid & 3;
        int ct = (bid >> 2) & 1;
        int kc = bid >> 3;          // [0, 64)
        if (tid < KC * 16 / 4)
            ((float4*)sh)[tid] = ((const float4*)(hT + (size_t)kc * KC * 16))[tid];
        __syncthreads();

        int base = o * HH;
        const float4* Cp = (const float4*)(C + (size_t)(base + kc * KC) * WTOT
                                             + base + ct * 1024) + tid;
        float acc[16][4];
#pragma unroll
        for (int b = 0; b < 16; ++b)
#pragma unroll
            for (int c = 0; c < 4; ++c) acc[b][c] = 0.0f;

#pragma unroll 4
        for (int k = 0; k < KC; ++k) {
            float4 c4 = Cp[(size_t)k * (WTOT / 4)];   // WTOT/4 == 2049 exact
#pragma unroll
            for (int b = 0; b < 16; ++b) {
                float hb = sh[k * 16 + b];            // LDS broadcast (free)
                acc[b][0] = fmaf(hb, c4.x, acc[b][0]);
                acc[b][1] = fmaf(hb, c4.y, acc[b][1]);
                acc[b][2] = fmaf(hb, c4.z, acc[b][2]);
                acc[b][3] = fmaf(hb, c4.w, acc[b][3]);
            }
        }

        // multiply by h[b, col] and reduce over the block's 1024 columns
        int col0 = ct * 1024 + 4 * tid;
        float v[16];
#pragma unroll
        for (int b = 0; b < 16; ++b) v[b] = 0.0f;
#pragma unroll
        for (int c = 0; c < 4; ++c) {
            const float* hc = hT + (size_t)(col0 + c) * 16;
#pragma unroll
            for (int b = 0; b < 16; ++b)
                v[b] = fmaf(acc[b][c], hc[b], v[b]);  // contiguous -> dwordx4
        }

#pragma unroll
        for (int b = 0; b < 16; ++b) {
            float s = v[b];
#pragma unroll
            for (int off = 32; off > 0; off >>= 1)
                s += __shfl_down(s, off, 64);
            v[b] = s;
        }
        int lane = tid & 63, wv = tid >> 6;
        if (lane == 0) {
#pragma unroll
            for (int b = 0; b < 16; ++b) red[wv * 16 + b] = v[b];
        }
        __syncthreads();
        if (tid < 16)
            qpart[bid * 16 + tid] = red[tid] + red[16 + tid] + red[32 + tid] + red[48 + tid];
    } else {
        int cb = bid - NQUAD;       // [0, 32)
        int o  = cb & 3;
        int kb = cb >> 2;           // [0, 8)
        int b = tid >> 4, g = tid & 15;
        int base = o * HH;
        float a12 = 0.0f, ap = 0.0f;
#pragma unroll 4
        for (int i = 0; i < 16; ++i) {
            int k = kb * 256 + i * 16 + g;
            float hv = hT[k * 16 + b];
            float c1 = C[(size_t)(base + k) * WTOT + OHH + o];   // C column (strided)
            float c2 = C[(size_t)(OHH + o) * WTOT + base + k];   // C row (contiguous)
            float w2 = W2[o * HH + k];
            a12 = fmaf(hv, c1 + c2, a12);
            ap  = fmaf(hv, w2, ap);
        }
#pragma unroll
        for (int off = 8; off > 0; off >>= 1) {
            a12 += __shfl_down(a12, off, 16);
            ap  += __shfl_down(ap, off, 16);
        }
        if (g == 0) {
            xu[cb * 16 + b] = a12;
            xp[cb * 16 + b] = ap;
        }
    }
}

// out[0..64) = predictions (b*4+o), out[64..128) = uncertainty
__global__ void k_final(const float* __restrict__ C,
                        const float* __restrict__ qpart,
                        const float* __restrict__ xu,
                        const float* __restrict__ xp,
                        const float* __restrict__ b2,
                        float* __restrict__ out) {
    int i = threadIdx.x;   // 64 threads
    int b = i >> 2, o = i & 3;
    float u = 0.0f, p = 0.0f;
    for (int q = o; q < NQUAD; q += 4) u += qpart[q * 16 + b];
    for (int c = o; c < NCROSS; c += 4) {
        u += xu[c * 16 + b];
        p += xp[c * 16 + b];
    }
    out[i] = p + b2[o];
    out[64 + i] = u + C[(size_t)(OHH + o) * WTOT + OHH + o];
}

extern "C" void kernel_launch(void* const* d_in, const int* in_sizes, int n_in,
                              void* d_out, int out_size, void* d_ws, size_t ws_size,
                              hipStream_t stream) {
    const float* x  = (const float*)d_in[0];
    const float* W1 = (const float*)d_in[1];
    const float* b1 = (const float*)d_in[2];
    const float* W2 = (const float*)d_in[3];
    const float* b2 = (const float*)d_in[4];
    const float* C  = (const float*)d_in[5];
    float* out = (float*)d_out;

    float* hT    = (float*)d_ws;            // 32768
    float* qpart = hT + HH * BB;            // 8192
    float* xu    = qpart + NQUAD * 16;      // 512
    float* xp    = xu + NCROSS * 16;        // 512

    hipLaunchKernelGGL(k_prep,  dim3(HH / 16),        dim3(256), 0, stream, x, W1, b1, hT);
    hipLaunchKernelGGL(k_main,  dim3(NQUAD + NCROSS), dim3(256), 0, stream, C, hT, W2, qpart, xu, xp);
    hipLaunchKernelGGL(k_final, dim3(1),              dim3(64),  0, stream, C, qpart, xu, xp, b2, out);
}

// Round 3
// 329.981 us; speedup vs baseline: 1.0976x; 1.0976x over previous
//
#include <hip/hip_runtime.h>

// Problem constants (B,D,H,O) = (16,128,2048,4), W = O*H+O = 8196
#define BB 16
#define DD 128
#define HH 2048
#define OO 4
#define WTOT 8196
#define OHH 8192   // O*H
#define KC 32      // k-rows per quad block
#define GG 8       // rows per staged group
#define NG (KC / GG)
#define NQUAD 512  // 4 o * 2 col-tiles * 64 kc
#define NCROSS 32  // 4 o * 8 k-blocks

typedef const __attribute__((address_space(1))) float glob_f;
typedef __attribute__((address_space(3))) float lds_f;

// ws layout (floats): hT[32768] | qpart[512*16] | xu[32*16] | xp[32*16]

// h = relu(x @ W1^T + b1), stored transposed: hT[j*16+b]
__global__ __launch_bounds__(256) void k_prep(const float* __restrict__ x,
                                              const float* __restrict__ W1,
                                              const float* __restrict__ b1,
                                              float* __restrict__ hT) {
    __shared__ float xs[DD * BB];   // xs[d*16+b]
    int tid = threadIdx.x;
    for (int i = tid; i < DD * BB; i += 256) {
        int b = i & 15, d = i >> 4;
        xs[i] = x[b * DD + d];
    }
    __syncthreads();
    int b = tid & 15;
    int j = blockIdx.x * 16 + (tid >> 4);
    const float4* W1v = (const float4*)(W1 + (size_t)j * DD);
    float acc = 0.0f;
#pragma unroll
    for (int dd = 0; dd < DD / 4; ++dd) {
        float4 w = W1v[dd];
        acc = fmaf(xs[(dd * 4 + 0) * 16 + b], w.x, acc);
        acc = fmaf(xs[(dd * 4 + 1) * 16 + b], w.y, acc);
        acc = fmaf(xs[(dd * 4 + 2) * 16 + b], w.z, acc);
        acc = fmaf(xs[(dd * 4 + 3) * 16 + b], w.w, acc);
    }
    acc += b1[j];
    hT[j * 16 + b] = acc > 0.0f ? acc : 0.0f;
}

// Blocks [0,512): quadratic form over diagonal HxH blocks of C, with
// double-buffered global_load_lds staging (32 KB groups in flight -> MLP).
// Blocks [512,544): bias cross terms + prediction partials.
__global__ __launch_bounds__(256, 2) void k_main(const float* __restrict__ C,
                                                 const float* __restrict__ hT,
                                                 const float* __restrict__ W2,
                                                 float* __restrict__ qpart,
                                                 float* __restrict__ xu,
                                                 float* __restrict__ xp) {
    __shared__ float bufs[2 * GG * 1024];   // 64 KB double buffer: [buf][row][1024 cols]
    __shared__ float sh[KC * BB];           // 2 KB staged h rows
    __shared__ float red[4 * BB];
    int bid = blockIdx.x;
    int tid = threadIdx.x;

    if (bid < NQUAD) {
        int o  = bid & 3;
        int ct = (bid >> 2) & 1;
        int kc = bid >> 3;          // [0, 64)
        int base = o * HH;
        int row0 = base + kc * KC;
        int col0 = base + ct * 1024;

        // stage h rows for this block (KC*16 floats)
        if (tid < KC * BB / 4)
            ((float4*)sh)[tid] = ((const float4*)(hT + (size_t)kc * KC * BB))[tid];

        // global source for this thread's 4 columns
        glob_f* gsrc = (glob_f*)(C + (size_t)row0 * WTOT + col0 + tid * 4);
        lds_f*  ld0  = (lds_f*)(bufs) + tid * 4;   // lane*16B + wave-uniform base

        // issue group 0
#pragma unroll
        for (int r = 0; r < GG; ++r)
            __builtin_amdgcn_global_load_lds(gsrc + (size_t)r * WTOT,
                                             ld0 + r * 1024, 16, 0, 0);

        float acc[16][4];
#pragma unroll
        for (int b = 0; b < 16; ++b)
#pragma unroll
            for (int c = 0; c < 4; ++c) acc[b][c] = 0.0f;

        for (int g = 0; g < NG; ++g) {
            __syncthreads();   // drains group g's loads (vmcnt 0) for ALL waves
            if (g + 1 < NG) {  // prefetch group g+1 into the other buffer
                glob_f* gs = gsrc + (size_t)(g + 1) * GG * WTOT;
                lds_f*  ls = (lds_f*)(bufs) + ((g + 1) & 1) * (GG * 1024) + tid * 4;
#pragma unroll
                for (int r = 0; r < GG; ++r)
                    __builtin_amdgcn_global_load_lds(gs + (size_t)r * WTOT,
                                                     ls + r * 1024, 16, 0, 0);
            }
            const float* bp = bufs + (g & 1) * (GG * 1024);
#pragma unroll
            for (int k = 0; k < GG; ++k) {
                float4 c4 = ((const float4*)(bp + k * 1024))[tid];
                int kk = g * GG + k;
#pragma unroll
                for (int b = 0; b < 16; ++b) {
                    float hb = sh[kk * 16 + b];       // broadcast, conflict-free
                    acc[b][0] = fmaf(hb, c4.x, acc[b][0]);
                    acc[b][1] = fmaf(hb, c4.y, acc[b][1]);
                    acc[b][2] = fmaf(hb, c4.z, acc[b][2]);
                    acc[b][3] = fmaf(hb, c4.w, acc[b][3]);
                }
            }
        }

        // multiply by h[b, col] and reduce over the block's 1024 columns
        int col0l = ct * 1024 + 4 * tid;
        float v[16];
#pragma unroll
        for (int b = 0; b < 16; ++b) v[b] = 0.0f;
#pragma unroll
        for (int c = 0; c < 4; ++c) {
            const float* hc = hT + (size_t)(col0l + c) * 16;
#pragma unroll
            for (int b = 0; b < 16; ++b)
                v[b] = fmaf(acc[b][c], hc[b], v[b]);
        }
#pragma unroll
        for (int b = 0; b < 16; ++b) {
            float s = v[b];
#pragma unroll
            for (int off = 32; off > 0; off >>= 1)
                s += __shfl_down(s, off, 64);
            v[b] = s;
        }
        int lane = tid & 63, wv = tid >> 6;
        if (lane == 0) {
#pragma unroll
            for (int b = 0; b < 16; ++b) red[wv * 16 + b] = v[b];
        }
        __syncthreads();
        if (tid < 16)
            qpart[bid * 16 + tid] = red[tid] + red[16 + tid] + red[32 + tid] + red[48 + tid];
    } else {
        int cb = bid - NQUAD;       // [0, 32)
        int o  = cb & 3;
        int kb = cb >> 2;           // [0, 8)
        int b = tid >> 4, g = tid & 15;
        int base = o * HH;
        float a12 = 0.0f, ap = 0.0f;
#pragma unroll 4
        for (int i = 0; i < 16; ++i) {
            int k = kb * 256 + i * 16 + g;
            float hv = hT[k * 16 + b];
            float c1 = C[(size_t)(base + k) * WTOT + OHH + o];   // C column (strided)
            float c2 = C[(size_t)(OHH + o) * WTOT + base + k];   // C row (contiguous)
            float w2 = W2[o * HH + k];
            a12 = fmaf(hv, c1 + c2, a12);
            ap  = fmaf(hv, w2, ap);
        }
#pragma unroll
        for (int off = 8; off > 0; off >>= 1) {
            a12 += __shfl_down(a12, off, 16);
            ap  += __shfl_down(ap, off, 16);
        }
        if (g == 0) {
            xu[cb * 16 + b] = a12;
            xp[cb * 16 + b] = ap;
        }
    }
}

// out[0..64) = predictions (b*4+o), out[64..128) = uncertainty
__global__ __launch_bounds__(256) void k_final(const float* __restrict__ C,
                                               const float* __restrict__ qpart,
                                               const float* __restrict__ xu,
                                               const float* __restrict__ xp,
                                               const float* __restrict__ b2,
                                               float* __restrict__ out) {
    __shared__ float s[256];
    int tid = threadIdx.x;      // 256
    int i = tid & 63;           // output index b*4+o
    int p = tid >> 6;           // partial slice 0..3
    int b = i >> 2, o = i & 3;
    float u = 0.0f;
#pragma unroll 4
    for (int m = p; m < NQUAD / 4; m += 4)       // qpart rows with q%4==o
        u += qpart[(o + 4 * m) * 16 + b];
    if (p == 0) {
#pragma unroll
        for (int c = o; c < NCROSS; c += 4) u += xu[c * 16 + b];
    }
    s[tid] = u;
    __syncthreads();
    if (tid < 64) {
        float uu = s[tid] + s[64 + tid] + s[128 + tid] + s[192 + tid];
        float pp = 0.0f;
#pragma unroll
        for (int c = o; c < NCROSS; c += 4) pp += xp[c * 16 + b];
        out[i] = pp + b2[o];
        out[64 + i] = uu + C[(size_t)(OHH + o) * WTOT + OHH + o];
    }
}

extern "C" void kernel_launch(void* const* d_in, const int* in_sizes, int n_in,
                              void* d_out, int out_size, void* d_ws, size_t ws_size,
                              hipStream_t stream) {
    const float* x  = (const float*)d_in[0];
    const float* W1 = (const float*)d_in[1];
    const float* b1 = (const float*)d_in[2];
    const float* W2 = (const float*)d_in[3];
    const float* b2 = (const float*)d_in[4];
    const float* C  = (const float*)d_in[5];
    float* out = (float*)d_out;

    float* hT    = (float*)d_ws;            // 32768
    float* qpart = hT + HH * BB;            // 8192
    float* xu    = qpart + NQUAD * 16;      // 512
    float* xp    = xu + NCROSS * 16;        // 512

    hipLaunchKernelGGL(k_prep,  dim3(HH / 16),        dim3(256), 0, stream, x, W1, b1, hT);
    hipLaunchKernelGGL(k_main,  dim3(NQUAD + NCROSS), dim3(256), 0, stream, C, hT, W2, qpart, xu, xp);
    hipLaunchKernelGGL(k_final, dim3(1),              dim3(256), 0, stream, C, qpart, xu, xp, b2, out);
}